// Round 6
// baseline (159.195 us; speedup 1.0000x reference)
//
#include <hip/hip_runtime.h>
#include <hip/hip_bf16.h>
#include <stdint.h>

typedef __attribute__((ext_vector_type(8))) short bf16x8;
typedef __attribute__((ext_vector_type(4))) float f32x4;
typedef __attribute__((ext_vector_type(4))) unsigned short u16x4;
typedef __attribute__((ext_vector_type(2))) unsigned int u32x2;

__device__ __forceinline__ float silu_f(float x) {
    return x * __builtin_amdgcn_rcpf(1.0f + __expf(-x));
}

// round-to-nearest-even f32 -> bf16
__device__ __forceinline__ unsigned short f2bf(float x) {
    union { float f; unsigned int u; } v; v.f = x;
    unsigned int r = v.u + 0x7fffu + ((v.u >> 16) & 1u);
    return (unsigned short)(r >> 16);
}
__device__ __forceinline__ float bf2f(unsigned short u) {
    union { unsigned int u; float f; } v; v.u = ((unsigned int)u) << 16;
    return v.f;
}

// async global->LDS, 16B per lane. LDS dest = wave-uniform base + lane*16.
__device__ __forceinline__ void async16(void* l, const void* g) {
    auto lds3 = (__attribute__((address_space(3))) unsigned int*)(uintptr_t)l;
    auto g1   = (const __attribute__((address_space(1))) unsigned int*)(uintptr_t)g;
    __builtin_amdgcn_global_load_lds(g1, lds3, 16, 0, 0);
}

// Precompute:
//   P1[t][o] = sum_k table[t][k] * W[k][o]       + b[o]   (bf16)
//   P2[t][o] = sum_k table[t][k] * W[128+k][o]            (bf16)
//   Wt3[o][k] = W[256+k][o]                               (bf16, transposed)
__global__ void prep_P(const int* __restrict__ code_idx,
                       const float* __restrict__ codebook,
                       const float* __restrict__ W,
                       const float* __restrict__ b,
                       unsigned short* __restrict__ P1,
                       unsigned short* __restrict__ P2,
                       unsigned short* __restrict__ Wt3)
{
    __shared__ float trow[128];
    const int t = blockIdx.x, tid = threadIdx.x;
    if (tid < 128) {
        int sym = code_idx[t * 8 + (tid >> 4)];
        trow[tid] = codebook[sym * 16 + (tid & 15)];
    } else {
        int k = tid - 128;                       // 0..127
        Wt3[t * 128 + k] = f2bf(W[(256 + k) * 128 + t]);
    }
    __syncthreads();
    const int which = tid >> 7, o = tid & 127;
    const float* Wb = W + which * 16384;
    float acc = which ? 0.0f : b[o];
#pragma unroll 8
    for (int k = 0; k < 128; ++k)
        acc += trow[k] * Wb[k * 128 + o];
    (which ? P2 : P1)[t * 128 + o] = f2bf(acc);
}

// Fused main, 64 edges per block, 512 threads = 8 waves, ONE barrier.
// Round-6 structure: round 5 proved the kernel is bound by a fixed serial
// chain per block (occupancy 25->48% moved duration only -8%; traffic-free
// replay identical). The chain was 2x __syncthreads, each draining all
// waves behind the slowest chase. Changes:
//  * phase 1 is now WAVE-LOCAL: each wave computes r for its OWN 16 edges
//    (the wn-pair computes the same rows redundantly -- identical bits, so
//    the duplicate LDS writes are benign) and needs only a wave-local
//    s_waitcnt lgkmcnt(0), NOT a block barrier.
//  * the chase (ei->x->P1/P2, the longest latency chain) is issued before
//    the single remaining barrier, whose mandatory vmcnt(0) drain absorbs
//    it off the critical path.
//  * after the one barrier each wave runs to completion with zero
//    cross-wave sync and zero VMEM dependencies (LDS + MFMA + stores).
//  * registers kept under the 6-waves/EU cap (~84): per-ks LDS fragment
//    reads (no Bf hoist), wr = 6 x float4 (each thread: 8 edges x 4 cols).
//   lB = Wt3 (128x128 bf16), async16-staged, chunk-swizzled.
//   lR = rbf tile (64 x 24B), async16-staged.
//   C^T = B @ A^T via SWAPPED mfma operands -> one edge/lane, float4
//   stores, ushort4 P-gathers. Stores PLAIN (cached): NT = round-1 regression.
__global__ __launch_bounds__(512, 6) void fused_main(
    const int* __restrict__ x,
    const float* __restrict__ rbf,
    const int* __restrict__ ei,
    const int* __restrict__ ej,
    const float* __restrict__ W_rbf,
    const float* __restrict__ b_rbf,
    const unsigned short* __restrict__ P1,
    const unsigned short* __restrict__ P2,
    const unsigned short* __restrict__ Wt3,
    float* __restrict__ out)
{
    __shared__ __align__(16) unsigned char lB[32768];  // Wt3 [128 rows][256B]
    __shared__ __align__(16) unsigned char lA[16384];  // r   [64 rows][256B]
    __shared__ __align__(16) unsigned char lR[1536];   // rbf [64 rows][24B]

    const int tid  = threadIdx.x;
    const int lane = tid & 63;
    const int w    = tid >> 6;          // 0..7
    const int e0   = blockIdx.x * 64;

    const int quad = lane >> 4, l15 = lane & 15, l7 = l15 & 7;
    const int wm = (w >> 1) * 16;       // 16-edge row group (pair-shared)
    const int wn = (w & 1) * 64;        // 64-col half

    // ---- chase FIRST: longest chain ei -> x -> P1/P2 (3 L2/L3 trips) ----
    int ti, tj;
    {
        int e = e0 + wm + l15;
        ti = x[ei[e]];
        tj = x[ej[e]];
    }

    // ---- async stages: lB (4/thread) + lR ----
    {   // B: physical chunk ch holds logical chunk ch ^ (o&7)
        const int ri = lane >> 4, ch = lane & 15;
#pragma unroll
        for (int rr = 0; rr < 4; ++rr) {
            int g = w * 4 + rr;           // 4-row group 0..31
            int o = g * 4 + ri;
            int jc = ch ^ (o & 7);
            async16(lB + g * 1024, Wt3 + o * 128 + jc * 8);
        }
    }
    if (w == 0)
        async16(lR, (const unsigned char*)rbf + (size_t)e0 * 24 + lane * 16);
    else if (w == 1 && lane < 32)
        async16(lR + 1024, (const unsigned char*)rbf + (size_t)e0 * 24 + 1024 + lane * 16);

    // ---- r-weights: each thread owns 4 cols (cb4) for 8 edges (h) ----
    const int cb4 = lane >> 1, h = lane & 1;
    float4 wr[6], br;
#pragma unroll
    for (int q = 0; q < 6; ++q)
        wr[q] = *(const float4*)(W_rbf + q * 128 + cb4 * 4);
    br = *(const float4*)(b_rbf + cb4 * 4);

    // ---- P gathers (depend on chase); drained by the barrier's vmcnt(0) ----
    u16x4 q1[4], q2[4];
#pragma unroll
    for (int ni = 0; ni < 4; ++ni) {
        int o = wn + ni * 16 + quad * 4;
        q1[ni] = *(const u16x4*)(P1 + ti * 128 + o);
        q2[ni] = *(const u16x4*)(P2 + tj * 128 + o);
    }

    __syncthreads();   // THE one barrier: lB + lR resident; q1/q2 also landed

    // ---- phase 1 (wave-local): 8 edges x 4 cols per thread -> lA ----
    // Both waves of a pair write identical bytes to the same rows (benign).
    const int ch16 = cb4 >> 1, halfoff = (cb4 & 1) * 8;
#pragma unroll
    for (int i = 0; i < 8; ++i) {
        int m = wm + h * 8 + i;
        const float* rr_ = (const float*)(lR + m * 24);
        float f0 = rr_[0], f1 = rr_[1], f2 = rr_[2],
              f3 = rr_[3], f4 = rr_[4], f5 = rr_[5];
        float a0 = br.x + f0*wr[0].x + f1*wr[1].x + f2*wr[2].x
                        + f3*wr[3].x + f4*wr[4].x + f5*wr[5].x;
        float a1 = br.y + f0*wr[0].y + f1*wr[1].y + f2*wr[2].y
                        + f3*wr[3].y + f4*wr[4].y + f5*wr[5].y;
        float a2 = br.z + f0*wr[0].z + f1*wr[1].z + f2*wr[2].z
                        + f3*wr[3].z + f4*wr[4].z + f5*wr[5].z;
        float a3 = br.w + f0*wr[0].w + f1*wr[1].w + f2*wr[2].w
                        + f3*wr[3].w + f4*wr[4].w + f5*wr[5].w;
        unsigned int lo = (unsigned int)f2bf(silu_f(a0))
                        | ((unsigned int)f2bf(silu_f(a1)) << 16);
        unsigned int hi = (unsigned int)f2bf(silu_f(a2))
                        | ((unsigned int)f2bf(silu_f(a3)) << 16);
        int p = ch16 ^ (m & 7);
        u32x2 pk; pk[0] = lo; pk[1] = hi;
        *(u32x2*)(lA + m * 256 + p * 16 + halfoff) = pk;
    }

    // wave-local visibility of lA (cross-lane within the wave): wait for our
    // own ds_writes; no block barrier needed. sched_barrier pins ordering.
    asm volatile("s_waitcnt lgkmcnt(0)" ::: "memory");
    __builtin_amdgcn_sched_barrier(0);

    // ---- phase 2: per-ks fragment reads + 16 MFMA ----
    f32x4 acc[4] = {};
#pragma unroll
    for (int ks = 0; ks < 4; ++ks) {
        const int p = (ks * 4 + quad) ^ l7;
        bf16x8 af = *(const bf16x8*)(lA + (wm + l15) * 256 + p * 16);
        bf16x8 bfv[4];
#pragma unroll
        for (int ni = 0; ni < 4; ++ni)
            bfv[ni] = *(const bf16x8*)(lB + (wn + ni * 16 + l15) * 256 + p * 16);
        // swapped operands: D = Wt3_tile . r_tile^T = C^T
        // lane: col = l15 = edge, rows = quad*4+reg = 4 consecutive o
#pragma unroll
        for (int ni = 0; ni < 4; ++ni)
            acc[ni] = __builtin_amdgcn_mfma_f32_16x16x32_bf16(
                bfv[ni], af, acc[ni], 0, 0, 0);
    }

    // ---- phase 3: epilogue — one edge/lane, float4 cached stores ----
    {
        size_t e = (size_t)(e0 + wm + l15);
        float* orow = out + e * 128 + wn;
#pragma unroll
        for (int ni = 0; ni < 4; ++ni) {
            f32x4 v;
#pragma unroll
            for (int r = 0; r < 4; ++r)
                v[r] = silu_f(acc[ni][r] + bf2f(q1[ni][r]) + bf2f(q2[ni][r]));
            *(f32x4*)(orow + ni * 16 + quad * 4) = v;
        }
    }
}

extern "C" void kernel_launch(void* const* d_in, const int* in_sizes, int n_in,
                              void* d_out, int out_size, void* d_ws, size_t ws_size,
                              hipStream_t stream) {
    const int*   x        = (const int*)d_in[0];
    const float* rbf      = (const float*)d_in[1];
    const int*   ei       = (const int*)d_in[2];
    const int*   ej       = (const int*)d_in[3];
    const int*   code_idx = (const int*)d_in[4];
    const float* codebook = (const float*)d_in[5];
    const float* W_rbf    = (const float*)d_in[6];
    const float* b_rbf    = (const float*)d_in[7];
    const float* W        = (const float*)d_in[8];
    const float* b        = (const float*)d_in[9];
    float* out = (float*)d_out;

    const int nE = in_sizes[2];                   // 160000

    if (ws_size < 98304) return;                  // P1 + P2 + Wt3, bf16
    unsigned short* P1  = (unsigned short*)d_ws;  // 32 KB
    unsigned short* P2  = P1 + 16384;             // 32 KB
    unsigned short* Wt3 = P2 + 16384;             // 32 KB

    prep_P<<<128, 256, 0, stream>>>(code_idx, codebook, W, b, P1, P2, Wt3);
    fused_main<<<nE / 64, 512, 0, stream>>>(x, rbf, ei, ej, W_rbf, b_rbf,
                                            P1, P2, Wt3, out);
}

// Round 7
// 142.274 us; speedup vs baseline: 1.1189x; 1.1189x over previous
//
#include <hip/hip_runtime.h>
#include <hip/hip_bf16.h>
#include <stdint.h>

typedef __attribute__((ext_vector_type(8))) short bf16x8;
typedef __attribute__((ext_vector_type(4))) float f32x4;
typedef __attribute__((ext_vector_type(4))) unsigned short u16x4;
typedef __attribute__((ext_vector_type(2))) unsigned int u32x2;

__device__ __forceinline__ float silu_f(float x) {
    return x * __builtin_amdgcn_rcpf(1.0f + __expf(-x));
}

// round-to-nearest-even f32 -> bf16
__device__ __forceinline__ unsigned short f2bf(float x) {
    union { float f; unsigned int u; } v; v.f = x;
    unsigned int r = v.u + 0x7fffu + ((v.u >> 16) & 1u);
    return (unsigned short)(r >> 16);
}
__device__ __forceinline__ float bf2f(unsigned short u) {
    union { unsigned int u; float f; } v; v.u = ((unsigned int)u) << 16;
    return v.f;
}

// async global->LDS, 16B per lane. LDS dest = wave-uniform base + lane*16.
__device__ __forceinline__ void async16(void* l, const void* g) {
    auto lds3 = (__attribute__((address_space(3))) unsigned int*)(uintptr_t)l;
    auto g1   = (const __attribute__((address_space(1))) unsigned int*)(uintptr_t)g;
    __builtin_amdgcn_global_load_lds(g1, lds3, 16, 0, 0);
}

// Precompute:
//   P1[t][o] = sum_k table[t][k] * W[k][o]       + b[o]   (bf16)
//   P2[t][o] = sum_k table[t][k] * W[128+k][o]            (bf16)
//   Wt3[o][k] = W[256+k][o]                               (bf16, transposed)
__global__ void prep_P(const int* __restrict__ code_idx,
                       const float* __restrict__ codebook,
                       const float* __restrict__ W,
                       const float* __restrict__ b,
                       unsigned short* __restrict__ P1,
                       unsigned short* __restrict__ P2,
                       unsigned short* __restrict__ Wt3)
{
    __shared__ float trow[128];
    const int t = blockIdx.x, tid = threadIdx.x;
    if (tid < 128) {
        int sym = code_idx[t * 8 + (tid >> 4)];
        trow[tid] = codebook[sym * 16 + (tid & 15)];
    } else {
        int k = tid - 128;                       // 0..127
        Wt3[t * 128 + k] = f2bf(W[(256 + k) * 128 + t]);
    }
    __syncthreads();
    const int which = tid >> 7, o = tid & 127;
    const float* Wb = W + which * 16384;
    float acc = which ? 0.0f : b[o];
#pragma unroll 8
    for (int k = 0; k < 128; ++k)
        acc += trow[k] * Wb[k * 128 + o];
    (which ? P2 : P1)[t * 128 + o] = f2bf(acc);
}

// Fused main, 64 edges per block, 256 threads = 4 waves, ONE barrier,
// NO redundant work (round-6's regression causes removed):
//  * each wave exclusively owns 16 edges (4 x 16 = 64). Phase 1 computes r
//    ONLY for the wave's own edges (32 outputs/thread, same block total as
//    the 2-barrier version) and writes the wave's own 16 lA rows, so phase
//    2 needs only a wave-local s_waitcnt lgkmcnt(0) -- the second block
//    barrier is deleted. sched_barrier(0) after the waitcnt is required
//    (hipcc otherwise hoists register-only MFMA past an inline-asm wait).
//  * each wave computes D for ALL 128 output cols of its 16 edges:
//    acc[8] f32x4, 32 MFMA/wave -- identical block totals to before.
//  * chase (ei->x->P1/P2, the longest chain) issued FIRST; P-gathers sit
//    before the barrier so its mandatory vmcnt(0) drain absorbs them.
//   lB = Wt3 (128x128 bf16), async16-staged, chunk-swizzled.
//   lR = rbf tile (64 x 24B), async16-staged.
//   C^T = B @ A^T via SWAPPED mfma operands -> one edge/lane, float4
//   stores, ushort4 P-gathers. Stores PLAIN (cached): NT = round-1
//   regression (synchronous HBM drain at ~2 TB/s).
__global__ __launch_bounds__(256, 3) void fused_main(
    const int* __restrict__ x,
    const float* __restrict__ rbf,
    const int* __restrict__ ei,
    const int* __restrict__ ej,
    const float* __restrict__ W_rbf,
    const float* __restrict__ b_rbf,
    const unsigned short* __restrict__ P1,
    const unsigned short* __restrict__ P2,
    const unsigned short* __restrict__ Wt3,
    float* __restrict__ out)
{
    __shared__ __align__(16) unsigned char lB[32768];  // Wt3 [128 rows][256B]
    __shared__ __align__(16) unsigned char lA[16384];  // r   [64 rows][256B]
    __shared__ __align__(16) unsigned char lR[1536];   // rbf [64 rows][24B]

    const int tid  = threadIdx.x;
    const int lane = tid & 63;
    const int w    = tid >> 6;          // 0..3
    const int e0   = blockIdx.x * 64;

    const int quad = lane >> 4, l15 = lane & 15, l7 = l15 & 7;
    const int wm = w * 16;              // wave's exclusive 16-edge group

    // ---- chase FIRST: longest chain ei -> x -> P1/P2 (3 L2/L3 trips) ----
    int ti, tj;
    {
        int e = e0 + wm + l15;
        ti = x[ei[e]];
        tj = x[ej[e]];
    }

    // ---- async stages: lB (8/thread) + lR ----
    {   // B: physical chunk ch holds logical chunk ch ^ (o&7)
        const int ri = lane >> 4, ch = lane & 15;
#pragma unroll
        for (int rr = 0; rr < 8; ++rr) {
            int g = w * 8 + rr;           // 4-row group 0..31
            int o = g * 4 + ri;
            int jc = ch ^ (o & 7);
            async16(lB + g * 1024, Wt3 + o * 128 + jc * 8);
        }
    }
    if (w == 0)
        async16(lR, (const unsigned char*)rbf + (size_t)e0 * 24 + lane * 16);
    else if (w == 1 && lane < 32)
        async16(lR + 1024, (const unsigned char*)rbf + (size_t)e0 * 24 + 1024 + lane * 16);

    // ---- r-weights: each thread owns 4 cols (cb4) for 8 edges (h) ----
    const int cb4 = lane >> 1, h = lane & 1;
    float4 wr[6], br;
#pragma unroll
    for (int q = 0; q < 6; ++q)
        wr[q] = *(const float4*)(W_rbf + q * 128 + cb4 * 4);
    br = *(const float4*)(b_rbf + cb4 * 4);

    // ---- P gathers (depend on chase); drained by the barrier's vmcnt(0) ----
    u16x4 q1[8], q2[8];
#pragma unroll
    for (int ni = 0; ni < 8; ++ni) {
        int o = ni * 16 + quad * 4;
        q1[ni] = *(const u16x4*)(P1 + ti * 128 + o);
        q2[ni] = *(const u16x4*)(P2 + tj * 128 + o);
    }

    __syncthreads();   // THE one barrier: lB + lR resident; q1/q2 landed too

    // ---- phase 1 (wave-local, exclusive): 8 edges x 4 cols per thread ----
    const int ch16 = cb4 >> 1, halfoff = (cb4 & 1) * 8;
#pragma unroll
    for (int i = 0; i < 8; ++i) {
        int m = wm + h * 8 + i;
        const float* rr_ = (const float*)(lR + m * 24);
        float f0 = rr_[0], f1 = rr_[1], f2 = rr_[2],
              f3 = rr_[3], f4 = rr_[4], f5 = rr_[5];
        float a0 = br.x + f0*wr[0].x + f1*wr[1].x + f2*wr[2].x
                        + f3*wr[3].x + f4*wr[4].x + f5*wr[5].x;
        float a1 = br.y + f0*wr[0].y + f1*wr[1].y + f2*wr[2].y
                        + f3*wr[3].y + f4*wr[4].y + f5*wr[5].y;
        float a2 = br.z + f0*wr[0].z + f1*wr[1].z + f2*wr[2].z
                        + f3*wr[3].z + f4*wr[4].z + f5*wr[5].z;
        float a3 = br.w + f0*wr[0].w + f1*wr[1].w + f2*wr[2].w
                        + f3*wr[3].w + f4*wr[4].w + f5*wr[5].w;
        unsigned int lo = (unsigned int)f2bf(silu_f(a0))
                        | ((unsigned int)f2bf(silu_f(a1)) << 16);
        unsigned int hi = (unsigned int)f2bf(silu_f(a2))
                        | ((unsigned int)f2bf(silu_f(a3)) << 16);
        int p = ch16 ^ (m & 7);
        u32x2 pk; pk[0] = lo; pk[1] = hi;
        *(u32x2*)(lA + m * 256 + p * 16 + halfoff) = pk;
    }

    // wave-local visibility of lA (this wave wrote all rows it will read):
    // wait for our own ds_writes; no block barrier. sched_barrier keeps the
    // compiler from hoisting the MFMAs above the wait (rule: inline-asm
    // lgkmcnt + register-only MFMA needs an explicit scheduling fence).
    asm volatile("s_waitcnt lgkmcnt(0)" ::: "memory");
    __builtin_amdgcn_sched_barrier(0);

    // ---- phase 2: per-ks fragment reads + 32 MFMA (all 128 cols) ----
    f32x4 acc[8] = {};
#pragma unroll
    for (int ks = 0; ks < 4; ++ks) {
        const int p = (ks * 4 + quad) ^ l7;
        bf16x8 af = *(const bf16x8*)(lA + (wm + l15) * 256 + p * 16);
#pragma unroll
        for (int ni = 0; ni < 8; ++ni) {
            bf16x8 bfv = *(const bf16x8*)(lB + (ni * 16 + l15) * 256 + p * 16);
            // swapped operands: D = Wt3_tile . r_tile^T = C^T
            // lane: col = l15 = edge, rows = quad*4+reg = 4 consecutive o
            acc[ni] = __builtin_amdgcn_mfma_f32_16x16x32_bf16(
                bfv, af, acc[ni], 0, 0, 0);
        }
    }

    // ---- phase 3: epilogue — one edge/lane, 8x float4 cached stores ----
    {
        size_t e = (size_t)(e0 + wm + l15);
        float* orow = out + e * 128;
#pragma unroll
        for (int ni = 0; ni < 8; ++ni) {
            f32x4 v;
#pragma unroll
            for (int r = 0; r < 4; ++r)
                v[r] = silu_f(acc[ni][r] + bf2f(q1[ni][r]) + bf2f(q2[ni][r]));
            *(f32x4*)(orow + ni * 16 + quad * 4) = v;
        }
    }
}

extern "C" void kernel_launch(void* const* d_in, const int* in_sizes, int n_in,
                              void* d_out, int out_size, void* d_ws, size_t ws_size,
                              hipStream_t stream) {
    const int*   x        = (const int*)d_in[0];
    const float* rbf      = (const float*)d_in[1];
    const int*   ei       = (const int*)d_in[2];
    const int*   ej       = (const int*)d_in[3];
    const int*   code_idx = (const int*)d_in[4];
    const float* codebook = (const float*)d_in[5];
    const float* W_rbf    = (const float*)d_in[6];
    const float* b_rbf    = (const float*)d_in[7];
    const float* W        = (const float*)d_in[8];
    const float* b        = (const float*)d_in[9];
    float* out = (float*)d_out;

    const int nE = in_sizes[2];                   // 160000

    if (ws_size < 98304) return;                  // P1 + P2 + Wt3, bf16
    unsigned short* P1  = (unsigned short*)d_ws;  // 32 KB
    unsigned short* P2  = P1 + 16384;             // 32 KB
    unsigned short* Wt3 = P2 + 16384;             // 32 KB

    prep_P<<<128, 256, 0, stream>>>(code_idx, codebook, W, b, P1, P2, Wt3);
    fused_main<<<nE / 64, 256, 0, stream>>>(x, rbf, ei, ej, W_rbf, b_rbf,
                                            P1, P2, Wt3, out);
}

// Round 8
// 136.837 us; speedup vs baseline: 1.1634x; 1.0397x over previous
//
#include <hip/hip_runtime.h>
#include <hip/hip_bf16.h>
#include <stdint.h>

typedef __attribute__((ext_vector_type(8))) short bf16x8;
typedef __attribute__((ext_vector_type(4))) float f32x4;

__device__ __forceinline__ float silu_f(float x) {
    return x * __builtin_amdgcn_rcpf(1.0f + __expf(-x));
}

// round-to-nearest-even f32 -> bf16
__device__ __forceinline__ unsigned short f2bf(float x) {
    union { float f; unsigned int u; } v; v.f = x;
    unsigned int r = v.u + 0x7fffu + ((v.u >> 16) & 1u);
    return (unsigned short)(r >> 16);
}
__device__ __forceinline__ float bf2f(unsigned short u) {
    union { unsigned int u; float f; } v; v.u = ((unsigned int)u) << 16;
    return v.f;
}

// async global->LDS, 16B per lane. LDS dest = wave-uniform base + lane*16.
__device__ __forceinline__ void async16(void* l, const void* g) {
    auto lds3 = (__attribute__((address_space(3))) unsigned int*)(uintptr_t)l;
    auto g1   = (const __attribute__((address_space(1))) unsigned int*)(uintptr_t)g;
    __builtin_amdgcn_global_load_lds(g1, lds3, 16, 0, 0);
}

// Precompute:
//   P1[t][o] = sum_k table[t][k] * W[k][o]       + b[o]   (bf16)
//   P2[t][o] = sum_k table[t][k] * W[128+k][o]            (bf16)
//   Wt3[o][k] = W[256+k][o]                               (bf16, transposed)
__global__ void prep_P(const int* __restrict__ code_idx,
                       const float* __restrict__ codebook,
                       const float* __restrict__ W,
                       const float* __restrict__ b,
                       unsigned short* __restrict__ P1,
                       unsigned short* __restrict__ P2,
                       unsigned short* __restrict__ Wt3)
{
    __shared__ float trow[128];
    const int t = blockIdx.x, tid = threadIdx.x;
    if (tid < 128) {
        int sym = code_idx[t * 8 + (tid >> 4)];
        trow[tid] = codebook[sym * 16 + (tid & 15)];
    } else {
        int k = tid - 128;                       // 0..127
        Wt3[t * 128 + k] = f2bf(W[(256 + k) * 128 + t]);
    }
    __syncthreads();
    const int which = tid >> 7, o = tid & 127;
    const float* Wb = W + which * 16384;
    float acc = which ? 0.0f : b[o];
#pragma unroll 8
    for (int k = 0; k < 128; ++k)
        acc += trow[k] * Wb[k * 128 + o];
    (which ? P2 : P1)[t * 128 + o] = f2bf(acc);
}

// Fused main, 64 edges per block, 256 threads (4 waves, 32x64 C-tile each):
//   lB = Wt3 (128x128 bf16, K=128), async16-staged, chunk-swizzled
//   lR = rbf tile (64 x 24B), async16-staged
//   lA = r = silu(rbf @ W_rbf + b_rbf) bf16, VALU-computed from lR
//   C = A @ B^T via mfma; epilogue adds register-prefetched P1[x_i]+P2[x_j].
// NOTE (session ledger): this exact configuration measured 132.9 (prior
// session) and 131.9 (round 0) -- the best end-to-end totals observed.
// Variants tried and measured WORSE in total: nontemporal stores (+18us:
// synchronous 108MB HBM drain at ~2TB/s), swapped-operand float4 epilogue
// (+10), 256-edge blocks (+21), direct-global B fragments (+14), 8-wave
// blocks (+10), barrier elimination (+0 vs swapped baseline). The timed
// window is dominated by harness poison-fill traffic (~2x51us at ~80% of
// achievable HBM BW); fused_main sits below that floor.
__global__ __launch_bounds__(256, 3) void fused_main(
    const int* __restrict__ x,
    const float* __restrict__ rbf,
    const int* __restrict__ ei,
    const int* __restrict__ ej,
    const float* __restrict__ W_rbf,
    const float* __restrict__ b_rbf,
    const unsigned short* __restrict__ P1,
    const unsigned short* __restrict__ P2,
    const unsigned short* __restrict__ Wt3,
    float* __restrict__ out)
{
    __shared__ __align__(16) unsigned char lB[32768];  // Wt3 [128 rows][256B]
    __shared__ __align__(16) unsigned char lA[16384];  // r   [64 rows][256B]
    __shared__ __align__(16) unsigned char lR[1536];   // rbf [64 rows][24B]

    const int tid  = threadIdx.x;
    const int lane = tid & 63;
    const int w    = tid >> 6;
    const int e0   = blockIdx.x * 64;

    const int quad = lane >> 4, l15 = lane & 15;
    const int wm = (w >> 1) * 32, wn = (w & 1) * 64;

    // ---- phase 0: async stages + index chase ----
    {   // B: physical chunk ch holds logical chunk ch ^ (o&7)
        const int ri = lane >> 4, ch = lane & 15;
#pragma unroll
        for (int rr = 0; rr < 8; ++rr) {
            int g = w * 8 + rr;           // 4-row group 0..31
            int o = g * 4 + ri;
            int j = ch ^ (o & 7);
            async16(lB + g * 1024, Wt3 + o * 128 + j * 8);
        }
    }
    // rbf tile: 1536B contiguous
    if (w == 0)
        async16(lR, (const unsigned char*)rbf + (size_t)e0 * 24 + lane * 16);
    else if (w == 1 && lane < 32)
        async16(lR + 1024, (const unsigned char*)rbf + (size_t)e0 * 24 + 1024 + lane * 16);

    // epilogue row indices: 8 rows per thread, chase x[ei[e]], x[ej[e]] now
    int ti[8], tj[8];
#pragma unroll
    for (int mi = 0; mi < 2; ++mi)
#pragma unroll
        for (int r = 0; r < 4; ++r) {
            int m = wm + mi * 16 + quad * 4 + r;
            int e = e0 + m;
            ti[mi * 4 + r] = x[ei[e]];
            tj[mi * 4 + r] = x[ej[e]];
        }

    // r-weights (L2-hot, identical for all blocks)
    const int j16 = tid & 15, gg = tid >> 4, cb = j16 * 8;
    float wr[6][8], br[8];
#pragma unroll
    for (int q = 0; q < 6; ++q) {
        const float4* p = (const float4*)(W_rbf + q * 128 + cb);
        float4 a = p[0], c = p[1];
        wr[q][0]=a.x; wr[q][1]=a.y; wr[q][2]=a.z; wr[q][3]=a.w;
        wr[q][4]=c.x; wr[q][5]=c.y; wr[q][6]=c.z; wr[q][7]=c.w;
    }
    {
        const float4* p = (const float4*)(b_rbf + cb);
        float4 a = p[0], c = p[1];
        br[0]=a.x; br[1]=a.y; br[2]=a.z; br[3]=a.w;
        br[4]=c.x; br[5]=c.y; br[6]=c.z; br[7]=c.w;
    }

    __syncthreads();   // drains async16 (B + rbf in LDS)

    // ---- phase 1: r-compute from lR -> lA (4 edges x 8 cols per thread) ----
#pragma unroll
    for (int i = 0; i < 4; ++i) {
        int m = gg * 4 + i;
        const float* rr_ = (const float*)(lR + m * 24);
        float f0 = rr_[0], f1 = rr_[1], f2 = rr_[2],
              f3 = rr_[3], f4 = rr_[4], f5 = rr_[5];
        bf16x8 pk;
#pragma unroll
        for (int c = 0; c < 8; ++c) {
            float a = br[c] + f0*wr[0][c] + f1*wr[1][c] + f2*wr[2][c]
                            + f3*wr[3][c] + f4*wr[4][c] + f5*wr[5][c];
            pk[c] = (short)f2bf(silu_f(a));
        }
        int p = j16 ^ (m & 7);
        *(bf16x8*)(lA + m * 256 + p * 16) = pk;
    }

    __syncthreads();

    // ---- phase 2: P prefetch (overlaps MFMA), then MFMA ----
    unsigned short q1[2][4][4], q2[2][4][4];
#pragma unroll
    for (int mi = 0; mi < 2; ++mi)
#pragma unroll
        for (int r = 0; r < 4; ++r) {
            const unsigned short* p1r = P1 + ti[mi * 4 + r] * 128;
            const unsigned short* p2r = P2 + tj[mi * 4 + r] * 128;
#pragma unroll
            for (int ni = 0; ni < 4; ++ni) {
                int o = wn + ni * 16 + l15;
                q1[mi][r][ni] = p1r[o];
                q2[mi][r][ni] = p2r[o];
            }
        }

    f32x4 acc[2][4] = {};
    const int l7 = l15 & 7;
#pragma unroll
    for (int ks = 0; ks < 4; ++ks) {
        const int j = ks * 4 + quad;
        const int p = j ^ l7;
        bf16x8 af[2], bfv[4];
#pragma unroll
        for (int mi = 0; mi < 2; ++mi)
            af[mi] = *(const bf16x8*)(lA + (wm + mi * 16 + l15) * 256 + p * 16);
#pragma unroll
        for (int ni = 0; ni < 4; ++ni)
            bfv[ni] = *(const bf16x8*)(lB + (wn + ni * 16 + l15) * 256 + p * 16);
#pragma unroll
        for (int mi = 0; mi < 2; ++mi)
#pragma unroll
            for (int ni = 0; ni < 4; ++ni)
                acc[mi][ni] = __builtin_amdgcn_mfma_f32_16x16x32_bf16(
                    af[mi], bfv[ni], acc[mi][ni], 0, 0, 0);
    }

    // ---- phase 3: epilogue ----
#pragma unroll
    for (int mi = 0; mi < 2; ++mi)
#pragma unroll
        for (int r = 0; r < 4; ++r) {
            int m = wm + mi * 16 + quad * 4 + r;
            size_t e = e0 + m;
#pragma unroll
            for (int ni = 0; ni < 4; ++ni) {
                int o = wn + ni * 16 + l15;
                float v = acc[mi][ni][r] + bf2f(q1[mi][r][ni]) + bf2f(q2[mi][r][ni]);
                out[e * 128 + o] = silu_f(v);
            }
        }
}

extern "C" void kernel_launch(void* const* d_in, const int* in_sizes, int n_in,
                              void* d_out, int out_size, void* d_ws, size_t ws_size,
                              hipStream_t stream) {
    const int*   x        = (const int*)d_in[0];
    const float* rbf      = (const float*)d_in[1];
    const int*   ei       = (const int*)d_in[2];
    const int*   ej       = (const int*)d_in[3];
    const int*   code_idx = (const int*)d_in[4];
    const float* codebook = (const float*)d_in[5];
    const float* W_rbf    = (const float*)d_in[6];
    const float* b_rbf    = (const float*)d_in[7];
    const float* W        = (const float*)d_in[8];
    const float* b        = (const float*)d_in[9];
    float* out = (float*)d_out;

    const int nE = in_sizes[2];                   // 160000

    if (ws_size < 98304) return;                  // P1 + P2 + Wt3, bf16
    unsigned short* P1  = (unsigned short*)d_ws;  // 32 KB
    unsigned short* P2  = P1 + 16384;             // 32 KB
    unsigned short* Wt3 = P2 + 16384;             // 32 KB

    prep_P<<<128, 256, 0, stream>>>(code_idx, codebook, W, b, P1, P2, Wt3);
    fused_main<<<nE / 64, 256, 0, stream>>>(x, rbf, ei, ej, W_rbf, b_rbf,
                                            P1, P2, Wt3, out);
}